// Round 2
// 33541.809 us; speedup vs baseline: 1.7050x; 1.7050x over previous
//
#include <hip/hip_runtime.h>
#include <math.h>

// Problem constants (from reference)
#define B_ 2
#define T_ 2048
#define D_ 1024
#define H_ 16
#define HD_ 64
#define L_ 8
#define DI_ 2048
#define VOCAB_ 32000
#define M_ (B_ * T_)          // 4096 rows
#define EPS_ 1e-6f

typedef _Float16 f16;
typedef __attribute__((ext_vector_type(4))) _Float16 f16x4;
typedef __attribute__((ext_vector_type(8))) _Float16 f16x8;
typedef __attribute__((ext_vector_type(4))) float f32x4;

// ---------------------------------------------------------------------------
// Embedding gather: x[row, :] = emb[idx[row], :]   (fp32 residual stream)
// ---------------------------------------------------------------------------
__global__ __launch_bounds__(256) void embed_kernel(
    const int* __restrict__ idx, const float* __restrict__ emb,
    float* __restrict__ x) {
  int row = blockIdx.x;
  int tok = idx[row];
  const float4* src = (const float4*)(emb + (size_t)tok * D_);
  float4* dst = (float4*)(x + (size_t)row * D_);
  dst[threadIdx.x] = src[threadIdx.x];
}

// ---------------------------------------------------------------------------
// fp32 -> fp16 cast (vectorized, grid-stride). n4 = elements/4.
// ---------------------------------------------------------------------------
__global__ __launch_bounds__(256) void cast_f16_kernel(
    const float* __restrict__ in, f16* __restrict__ out, long n4) {
  long i = (long)blockIdx.x * 256 + threadIdx.x;
  long stride = (long)gridDim.x * 256;
  for (; i < n4; i += stride) {
    float4 v = ((const float4*)in)[i];
    f16x4 o = {(f16)v.x, (f16)v.y, (f16)v.z, (f16)v.w};
    ((f16x4*)out)[i] = o;
  }
}

// ---------------------------------------------------------------------------
// RMSNorm fp32 in -> fp16 out. grid = M_, block = 256 (4 elems/thread)
// ---------------------------------------------------------------------------
__global__ __launch_bounds__(256) void rmsnorm_kernel(
    const float* __restrict__ x, const float* __restrict__ w,
    f16* __restrict__ out) {
  int row = blockIdx.x;
  float4 v = ((const float4*)(x + (size_t)row * D_))[threadIdx.x];
  float ss = v.x * v.x + v.y * v.y + v.z * v.z + v.w * v.w;
  #pragma unroll
  for (int off = 32; off; off >>= 1) ss += __shfl_xor(ss, off, 64);
  __shared__ float red[4];
  int wid = threadIdx.x >> 6;
  if ((threadIdx.x & 63) == 0) red[wid] = ss;
  __syncthreads();
  float tot = red[0] + red[1] + red[2] + red[3];
  float rms = rsqrtf(tot * (1.0f / D_) + EPS_);
  float4 wv = ((const float4*)w)[threadIdx.x];
  f16x4 o = {(f16)(v.x * rms * wv.x), (f16)(v.y * rms * wv.y),
             (f16)(v.z * rms * wv.z), (f16)(v.w * rms * wv.w)};
  ((f16x4*)(out + (size_t)row * D_))[threadIdx.x] = o;
}

// ---------------------------------------------------------------------------
// fp16 MFMA GEMM (m97 structure): C[M,N] = A[M,K] @ W[N,K]^T, fp32 accum.
// 128x128 tile, BK=32, 256 threads = 4 waves, each wave a 64x64 quadrant
// as 4x4 grid of 16x16x32 MFMA fragments. global_load_lds width=16 staging.
// omode: 0 = fp32 C, 1 = fp32 C = R + acc (residual), 2 = fp16 C.
// Requires: M%128==0, N%128==0, K%32==0, grid = (M/128)*(N/128), grid%8==0.
// ---------------------------------------------------------------------------
#define BM 128
#define BN 128
#define BK 32

__device__ __forceinline__ void gld16(const f16* g, f16* l) {
  __builtin_amdgcn_global_load_lds(
      (const __attribute__((address_space(1))) void*)g,
      (__attribute__((address_space(3))) void*)l, 16, 0, 0);
}

__global__ __launch_bounds__(256, 3) void gemm_f16(
    const f16* __restrict__ A, const f16* __restrict__ W,
    void* __restrict__ Cout, const float* __restrict__ R,
    int N, int K, int nbx, int omode) {
  __shared__ __attribute__((aligned(16))) f16 As[BM * BK];
  __shared__ __attribute__((aligned(16))) f16 Ws[BN * BK];

  // XCD-aware swizzle (grid % 8 == 0 for every call site)
  int nwg = gridDim.x;
  int qq = nwg >> 3;
  int bid = blockIdx.x;
  int swz = (bid & 7) * qq + (bid >> 3);
  int by = swz / nbx, bx = swz - by * nbx;
  int row0 = by * BM, col0 = bx * BN;

  int tid = threadIdx.x;
  int lane = tid & 63, wv = tid >> 6;
  int wr = wv >> 1, wc = wv & 1;       // wave quadrant (2x2 of 64x64)
  int lr16 = lane & 15, kg = lane >> 4;

  // staging: each wave DMAs 16 rows per call (lane -> row l>>2, col (l&3)*8)
  int srow = wv * 16 + (lane >> 2);
  int scol = (lane & 3) * 8;
  const f16* Ag = A + (size_t)(row0 + srow) * K + scol;
  const f16* Wg = W + (size_t)(col0 + srow) * K + scol;
  f16* AsW = As + wv * 16 * BK;
  f16* WsW = Ws + wv * 16 * BK;

  f32x4 acc[4][4] = {};

  for (int kt = 0; kt < K; kt += BK) {
    gld16(Ag + kt, AsW);
    gld16(Ag + (size_t)64 * K + kt, AsW + 64 * BK);
    gld16(Wg + kt, WsW);
    gld16(Wg + (size_t)64 * K + kt, WsW + 64 * BK);
    __syncthreads();   // compiler emits vmcnt(0) drain before barrier
    f16x8 af[4], bfr[4];
    #pragma unroll
    for (int m = 0; m < 4; ++m)
      af[m] = *(const f16x8*)&As[(wr * 64 + m * 16 + lr16) * BK + kg * 8];
    #pragma unroll
    for (int n = 0; n < 4; ++n)
      bfr[n] = *(const f16x8*)&Ws[(wc * 64 + n * 16 + lr16) * BK + kg * 8];
    #pragma unroll
    for (int m = 0; m < 4; ++m) {
      #pragma unroll
      for (int n = 0; n < 4; ++n)
        acc[m][n] = __builtin_amdgcn_mfma_f32_16x16x32_f16(
            af[m], bfr[n], acc[m][n], 0, 0, 0);
    }
    __syncthreads();
  }

  // C/D layout: col = lane&15, row = (lane>>4)*4 + reg  [m89-verified]
  int crow = kg * 4;
  #pragma unroll
  for (int m = 0; m < 4; ++m) {
    #pragma unroll
    for (int n = 0; n < 4; ++n) {
      #pragma unroll
      for (int r = 0; r < 4; ++r) {
        size_t ro = (size_t)(row0 + wr * 64 + m * 16 + crow + r) * N
                    + col0 + wc * 64 + n * 16 + lr16;
        float v = acc[m][n][r];
        if (omode == 0)      ((float*)Cout)[ro] = v;
        else if (omode == 1) ((float*)Cout)[ro] = R[ro] + v;
        else                 ((f16*)Cout)[ro]   = (f16)v;
      }
    }
  }
}

// ---------------------------------------------------------------------------
// Causal flash attention, fp32 compute from fp16 qkv, fp16 out.
// Block = 256 thr (4 waves) per (b, h, 64-query tile). K/V staged in LDS per
// 64-key chunk; each wave owns 16 query rows, online softmax in registers.
// Ks row-major (pad 68) for b128 row reads; V transposed [d][k] for b128 PV.
// qkv layout: [M, 3, H, HD] fp16.
// ---------------------------------------------------------------------------
__global__ __launch_bounds__(256) void attn_kernel(
    const f16* __restrict__ qkv, f16* __restrict__ yh) {
  __shared__ __attribute__((aligned(16))) float Ks[64][68];
  __shared__ __attribute__((aligned(16))) float Vt[64][68];
  __shared__ __attribute__((aligned(16))) float Qs[64][68];
  __shared__ __attribute__((aligned(16))) float Ps[4][64];

  int qb = blockIdx.x, bh = blockIdx.y;
  int h = bh & (H_ - 1), b = bh >> 4;
  int q0 = qb * 64;
  int tid = threadIdx.x;
  int lane = tid & 63, wv = tid >> 6;

  // stage Q tile (pre-scaled by 1/sqrt(HD))
  #pragma unroll
  for (int p = 0; p < 4; ++p) {
    int fid = p * 256 + tid;
    int r = fid >> 4, d4 = (fid & 15) * 4;
    const f16* qp = qkv + ((size_t)(b * T_ + q0 + r) * 3 + 0) * D_ + h * HD_ + d4;
    f16x4 q4 = *(const f16x4*)qp;
    *(float4*)&Qs[r][d4] = make_float4((float)q4.x * 0.125f, (float)q4.y * 0.125f,
                                       (float)q4.z * 0.125f, (float)q4.w * 0.125f);
  }

  float mi[16], li[16], ai[16];
  #pragma unroll
  for (int i = 0; i < 16; ++i) { mi[i] = -INFINITY; li[i] = 0.f; ai[i] = 0.f; }

  for (int k0 = 0; k0 <= q0; k0 += 64) {
    __syncthreads();  // prev chunk's reads done (also publishes Qs on iter 0)
    #pragma unroll
    for (int p = 0; p < 4; ++p) {
      int fid = p * 256 + tid;
      int r = fid >> 4, d4 = (fid & 15) * 4;
      const f16* kp = qkv + ((size_t)(b * T_ + k0 + r) * 3 + 1) * D_ + h * HD_ + d4;
      f16x4 k4 = *(const f16x4*)kp;
      f16x4 v4 = *(const f16x4*)(kp + D_);
      *(float4*)&Ks[r][d4] = make_float4((float)k4.x, (float)k4.y,
                                         (float)k4.z, (float)k4.w);
      Vt[d4 + 0][r] = (float)v4.x;
      Vt[d4 + 1][r] = (float)v4.y;
      Vt[d4 + 2][r] = (float)v4.z;
      Vt[d4 + 3][r] = (float)v4.w;
    }
    __syncthreads();

    #pragma unroll
    for (int i = 0; i < 16; ++i) {
      int qrow = wv * 16 + i;
      // scores: lane = key index in chunk
      float s = 0.f;
      #pragma unroll
      for (int d4 = 0; d4 < 64; d4 += 4) {
        float4 kk = *(const float4*)&Ks[lane][d4];
        float4 qv = *(const float4*)&Qs[qrow][d4];   // broadcast read
        s += kk.x * qv.x + kk.y * qv.y + kk.z * qv.z + kk.w * qv.w;
      }
      s = (k0 + lane <= q0 + qrow) ? s : -INFINITY;
      float red = s;
      #pragma unroll
      for (int off = 32; off; off >>= 1)
        red = fmaxf(red, __shfl_xor(red, off, 64));
      float newm = fmaxf(mi[i], red);
      float alpha = __expf(mi[i] - newm);   // exp(-inf)=0 first chunk
      float pv = __expf(s - newm);          // masked lanes -> 0
      float ps = pv;
      #pragma unroll
      for (int off = 32; off; off >>= 1) ps += __shfl_xor(ps, off, 64);
      li[i] = li[i] * alpha + ps;
      Ps[wv][lane] = pv;                    // per-wave P row (in-wave ordering)
      // PV: lane = head-dim index
      float accd = ai[i] * alpha;
      #pragma unroll
      for (int l4 = 0; l4 < 64; l4 += 4) {
        float4 pp = *(const float4*)&Ps[wv][l4];     // broadcast read
        float4 vv = *(const float4*)&Vt[lane][l4];
        accd += pp.x * vv.x + pp.y * vv.y + pp.z * vv.z + pp.w * vv.w;
      }
      ai[i] = accd;
      mi[i] = newm;
    }
  }
  #pragma unroll
  for (int i = 0; i < 16; ++i) {
    int qi = q0 + wv * 16 + i;
    yh[(size_t)(b * T_ + qi) * D_ + h * HD_ + lane] = (f16)(ai[i] / li[i]);
  }
}

// ---------------------------------------------------------------------------
// FFN elementwise: g = silu(g) * u   (fp16, 4 elems/thread)
// ---------------------------------------------------------------------------
__global__ __launch_bounds__(256) void silu_mul_kernel(
    f16* __restrict__ g, const f16* __restrict__ u, long n4) {
  long i = (long)blockIdx.x * 256 + threadIdx.x;
  if (i < n4) {
    f16x4 gv = ((const f16x4*)g)[i];
    f16x4 uv = ((const f16x4*)u)[i];
    f16x4 o;
    #pragma unroll
    for (int j = 0; j < 4; ++j) {
      float gf = (float)gv[j];
      float sf = gf / (1.f + __expf(-gf));
      o[j] = (f16)(sf * (float)uv[j]);
    }
    ((f16x4*)g)[i] = o;
  }
}

// ---------------------------------------------------------------------------
extern "C" void kernel_launch(void* const* d_in, const int* in_sizes, int n_in,
                              void* d_out, int out_size, void* d_ws,
                              size_t ws_size, hipStream_t stream) {
  const int* idx = (const int*)d_in[0];
  const float* emb = (const float*)d_in[1];
  const float* ln1 = (const float*)d_in[2];
  const float* qkvw = (const float*)d_in[3];
  const float* ow  = (const float*)d_in[4];
  const float* ln2 = (const float*)d_in[5];
  const float* gw  = (const float*)d_in[6];
  const float* uw  = (const float*)d_in[7];
  const float* dw  = (const float*)d_in[8];
  const float* lnf = (const float*)d_in[9];
  float* out = (float*)d_out;

  // workspace carve (total 149,422,080 B; prev kernel carved 150,994,944 B)
  char* p = (char*)d_ws;
  float* x   = (float*)p;  p += (size_t)M_ * D_ * 4;        // fp32 residual
  f16* qkvh  = (f16*)p;    p += (size_t)M_ * 3 * D_ * 2;    // fp16 qkv
  f16* hh    = (f16*)p;    p += (size_t)M_ * D_ * 2;        // fp16 h / y
  f16* gateh = (f16*)p;    p += (size_t)M_ * DI_ * 2;
  f16* uph   = (f16*)p;    p += (size_t)M_ * DI_ * 2;
  f16* wcast = (f16*)p;    // 65,536,000 B scratch: per-layer weights / emb

  embed_kernel<<<M_, 256, 0, stream>>>(idx, emb, x);

  for (int l = 0; l < L_; ++l) {
    f16* wq   = wcast;
    f16* wo_h = wq   + (size_t)3 * D_ * D_;
    f16* wg_h = wo_h + (size_t)D_ * D_;
    f16* wu_h = wg_h + (size_t)DI_ * D_;
    f16* wd_h = wu_h + (size_t)DI_ * D_;
    cast_f16_kernel<<<2048, 256, 0, stream>>>(qkvw + (size_t)l * 3 * D_ * D_, wq,   (long)(3 * D_ * D_ / 4));
    cast_f16_kernel<<<2048, 256, 0, stream>>>(ow   + (size_t)l * D_ * D_,     wo_h, (long)(D_ * D_ / 4));
    cast_f16_kernel<<<2048, 256, 0, stream>>>(gw   + (size_t)l * DI_ * D_,    wg_h, (long)(DI_ * D_ / 4));
    cast_f16_kernel<<<2048, 256, 0, stream>>>(uw   + (size_t)l * DI_ * D_,    wu_h, (long)(DI_ * D_ / 4));
    cast_f16_kernel<<<2048, 256, 0, stream>>>(dw   + (size_t)l * D_ * DI_,    wd_h, (long)(D_ * DI_ / 4));

    // h = rmsnorm(x, ln1) -> fp16
    rmsnorm_kernel<<<M_, 256, 0, stream>>>(x, ln1 + (size_t)l * D_, hh);
    // qkv = h @ qkv_w^T (fp16 out)
    gemm_f16<<<(3 * D_ / BN) * (M_ / BM), 256, 0, stream>>>(
        hh, wq, qkvh, nullptr, 3 * D_, D_, 3 * D_ / BN, 2);
    // attention -> hh (fp16)
    attn_kernel<<<dim3(T_ / 64, B_ * H_), 256, 0, stream>>>(qkvh, hh);
    // x = x + y @ o_w^T
    gemm_f16<<<(D_ / BN) * (M_ / BM), 256, 0, stream>>>(
        hh, wo_h, x, x, D_, D_, D_ / BN, 1);
    // h = rmsnorm(x, ln2) -> fp16
    rmsnorm_kernel<<<M_, 256, 0, stream>>>(x, ln2 + (size_t)l * D_, hh);
    // gate/up (fp16 out)
    gemm_f16<<<(DI_ / BN) * (M_ / BM), 256, 0, stream>>>(
        hh, wg_h, gateh, nullptr, DI_, D_, DI_ / BN, 2);
    gemm_f16<<<(DI_ / BN) * (M_ / BM), 256, 0, stream>>>(
        hh, wu_h, uph, nullptr, DI_, D_, DI_ / BN, 2);
    // gate = silu(gate) * up
    silu_mul_kernel<<<8192, 256, 0, stream>>>(gateh, uph, (long)((size_t)M_ * DI_ / 4));
    // x = x + gate @ down_w^T
    gemm_f16<<<(D_ / BN) * (M_ / BM), 256, 0, stream>>>(
        gateh, wd_h, x, x, D_, DI_, D_ / BN, 1);
  }

  // final norm + logits (fp32 out)
  rmsnorm_kernel<<<M_, 256, 0, stream>>>(x, lnf, hh);
  cast_f16_kernel<<<2048, 256, 0, stream>>>(emb, wcast, (long)((size_t)VOCAB_ * D_ / 4));
  gemm_f16<<<(VOCAB_ / BN) * (M_ / BM), 256, 0, stream>>>(
      hh, wcast, out, nullptr, VOCAB_, D_, VOCAB_ / BN, 0);
}

// Round 3
// 3537.922 us; speedup vs baseline: 16.1644x; 9.4807x over previous
//
#include <hip/hip_runtime.h>
#include <math.h>

// Problem constants (from reference)
#define B_ 2
#define T_ 2048
#define D_ 1024
#define H_ 16
#define HD_ 64
#define L_ 8
#define DI_ 2048
#define VOCAB_ 32000
#define M_ (B_ * T_)          // 4096 rows
#define EPS_ 1e-6f

typedef _Float16 f16;
typedef __attribute__((ext_vector_type(4))) _Float16 f16x4;
typedef __attribute__((ext_vector_type(8))) _Float16 f16x8;
typedef __attribute__((ext_vector_type(4))) float f32x4;

// ---------------------------------------------------------------------------
// Embedding gather: x[row, :] = emb[idx[row], :]   (fp32 residual stream)
// ---------------------------------------------------------------------------
__global__ __launch_bounds__(256) void embed_kernel(
    const int* __restrict__ idx, const float* __restrict__ emb,
    float* __restrict__ x) {
  int row = blockIdx.x;
  int tok = idx[row];
  const float4* src = (const float4*)(emb + (size_t)tok * D_);
  float4* dst = (float4*)(x + (size_t)row * D_);
  dst[threadIdx.x] = src[threadIdx.x];
}

// ---------------------------------------------------------------------------
// fp32 -> fp16 cast (vectorized, grid-stride). n4 = elements/4.
// ---------------------------------------------------------------------------
__global__ __launch_bounds__(256) void cast_f16_kernel(
    const float* __restrict__ in, f16* __restrict__ out, long n4) {
  long i = (long)blockIdx.x * 256 + threadIdx.x;
  long stride = (long)gridDim.x * 256;
  for (; i < n4; i += stride) {
    float4 v = ((const float4*)in)[i];
    f16x4 o = {(f16)v.x, (f16)v.y, (f16)v.z, (f16)v.w};
    ((f16x4*)out)[i] = o;
  }
}

// ---------------------------------------------------------------------------
// RMSNorm fp32 in -> fp16 out. grid = M_, block = 256 (4 elems/thread)
// ---------------------------------------------------------------------------
__global__ __launch_bounds__(256) void rmsnorm_kernel(
    const float* __restrict__ x, const float* __restrict__ w,
    f16* __restrict__ out) {
  int row = blockIdx.x;
  float4 v = ((const float4*)(x + (size_t)row * D_))[threadIdx.x];
  float ss = v.x * v.x + v.y * v.y + v.z * v.z + v.w * v.w;
  #pragma unroll
  for (int off = 32; off; off >>= 1) ss += __shfl_xor(ss, off, 64);
  __shared__ float red[4];
  int wid = threadIdx.x >> 6;
  if ((threadIdx.x & 63) == 0) red[wid] = ss;
  __syncthreads();
  float tot = red[0] + red[1] + red[2] + red[3];
  float rms = rsqrtf(tot * (1.0f / D_) + EPS_);
  float4 wv = ((const float4*)w)[threadIdx.x];
  f16x4 o = {(f16)(v.x * rms * wv.x), (f16)(v.y * rms * wv.y),
             (f16)(v.z * rms * wv.z), (f16)(v.w * rms * wv.w)};
  ((f16x4*)(out + (size_t)row * D_))[threadIdx.x] = o;
}

// ---------------------------------------------------------------------------
// fp16 MFMA GEMM (m97 structure): C[M,N] = A[M,K] @ W[N,K]^T, fp32 accum.
// 128x128 tile, BK=32, 256 threads = 4 waves, each wave a 64x64 quadrant.
// omode: 0 = fp32 C, 1 = fp32 C = R + acc (residual), 2 = fp16 C.
// ---------------------------------------------------------------------------
#define BM 128
#define BN 128
#define BK 32

__device__ __forceinline__ void gld16(const f16* g, f16* l) {
  __builtin_amdgcn_global_load_lds(
      (const __attribute__((address_space(1))) void*)g,
      (__attribute__((address_space(3))) void*)l, 16, 0, 0);
}

__global__ __launch_bounds__(256, 3) void gemm_f16(
    const f16* __restrict__ A, const f16* __restrict__ W,
    void* __restrict__ Cout, const float* __restrict__ R,
    int N, int K, int nbx, int omode) {
  __shared__ __attribute__((aligned(16))) f16 As[BM * BK];
  __shared__ __attribute__((aligned(16))) f16 Ws[BN * BK];

  int nwg = gridDim.x;
  int qq = nwg >> 3;
  int bid = blockIdx.x;
  int swz = (bid & 7) * qq + (bid >> 3);
  int by = swz / nbx, bx = swz - by * nbx;
  int row0 = by * BM, col0 = bx * BN;

  int tid = threadIdx.x;
  int lane = tid & 63, wv = tid >> 6;
  int wr = wv >> 1, wc = wv & 1;
  int lr16 = lane & 15, kg = lane >> 4;

  int srow = wv * 16 + (lane >> 2);
  int scol = (lane & 3) * 8;
  const f16* Ag = A + (size_t)(row0 + srow) * K + scol;
  const f16* Wg = W + (size_t)(col0 + srow) * K + scol;
  f16* AsW = As + wv * 16 * BK;
  f16* WsW = Ws + wv * 16 * BK;

  f32x4 acc[4][4] = {};

  for (int kt = 0; kt < K; kt += BK) {
    gld16(Ag + kt, AsW);
    gld16(Ag + (size_t)64 * K + kt, AsW + 64 * BK);
    gld16(Wg + kt, WsW);
    gld16(Wg + (size_t)64 * K + kt, WsW + 64 * BK);
    __syncthreads();
    f16x8 af[4], bfr[4];
    #pragma unroll
    for (int m = 0; m < 4; ++m)
      af[m] = *(const f16x8*)&As[(wr * 64 + m * 16 + lr16) * BK + kg * 8];
    #pragma unroll
    for (int n = 0; n < 4; ++n)
      bfr[n] = *(const f16x8*)&Ws[(wc * 64 + n * 16 + lr16) * BK + kg * 8];
    #pragma unroll
    for (int m = 0; m < 4; ++m) {
      #pragma unroll
      for (int n = 0; n < 4; ++n)
        acc[m][n] = __builtin_amdgcn_mfma_f32_16x16x32_f16(
            af[m], bfr[n], acc[m][n], 0, 0, 0);
    }
    __syncthreads();
  }

  int crow = kg * 4;
  #pragma unroll
  for (int m = 0; m < 4; ++m) {
    #pragma unroll
    for (int n = 0; n < 4; ++n) {
      #pragma unroll
      for (int r = 0; r < 4; ++r) {
        size_t ro = (size_t)(row0 + wr * 64 + m * 16 + crow + r) * N
                    + col0 + wc * 64 + n * 16 + lr16;
        float v = acc[m][n][r];
        if (omode == 0)      ((float*)Cout)[ro] = v;
        else if (omode == 1) ((float*)Cout)[ro] = R[ro] + v;
        else                 ((f16*)Cout)[ro]   = (f16)v;
      }
    }
  }
}

// ---------------------------------------------------------------------------
// V transpose: vt[(b*H+h)*HD + d][t] = qkv[b,t,2,h,d].  64x64 f16 LDS tiles.
// grid = (T/64, B*H), 256 threads.
// ---------------------------------------------------------------------------
__global__ __launch_bounds__(256) void vtrans_kernel(
    const f16* __restrict__ qkv, f16* __restrict__ vt) {
  __shared__ f16 tile[64][72];   // +8 f16 pad (16 B) keeps rows 16B-aligned
  int t0 = blockIdx.x * 64;
  int bh = blockIdx.y;
  int h = bh & (H_ - 1), b = bh >> 4;
  int tid = threadIdx.x;
  int r = tid >> 2, c8 = (tid & 3) * 16;
  const f16* src = qkv + ((size_t)(b * T_ + t0 + r) * 3 + 2) * D_ + h * HD_;
  *(f16x8*)&tile[r][c8]     = *(const f16x8*)(src + c8);
  *(f16x8*)&tile[r][c8 + 8] = *(const f16x8*)(src + c8 + 8);
  __syncthreads();
  int d = tid >> 2, k8 = (tid & 3) * 16;
  f16 vbuf[16];
  #pragma unroll
  for (int j = 0; j < 16; ++j) vbuf[j] = tile[k8 + j][d];
  f16* dst = vt + ((size_t)bh * HD_ + d) * T_ + t0 + k8;
  *(f16x8*)dst       = *(f16x8*)&vbuf[0];
  *(f16x8*)(dst + 8) = *(f16x8*)&vbuf[8];
}

// ---------------------------------------------------------------------------
// MFMA causal flash attention. Block = 256 thr (4 waves) per (b,h,64-q tile).
// Each wave: 16 q-rows. Q in registers (A-frags). K, V^T chunks (64x64 f16)
// staged via global_load_lds with XOR-swizzled SOURCE (linear LDS dest,
// col8 ^= row&7) so b128 fragment reads are conflict-free. S = QK^T via
// 8 MFMAs; fp32 online softmax (16-lane-group shfl reduce); P transposed
// C-layout -> A-layout through a 2KB per-wave LDS buffer; PV via 8 MFMAs.
// qkv layout [M,3,H,HD] f16; vt layout [B*H*HD, T] f16.
// ---------------------------------------------------------------------------
__device__ __forceinline__ int aswz(int row, int byte_in_row) {
  return row * 128 + (byte_in_row ^ ((row & 7) << 4));
}

__global__ __launch_bounds__(256) void attn_mfma_kernel(
    const f16* __restrict__ qkv, const f16* __restrict__ vt,
    f16* __restrict__ yh) {
  __shared__ __attribute__((aligned(16))) char KsB[64 * 128];
  __shared__ __attribute__((aligned(16))) char VsB[64 * 128];
  __shared__ __attribute__((aligned(16))) char PsB[4 * 16 * 128];

  int bh = blockIdx.x;                 // b*H + h  (x-dim: balances causal skew)
  int qb = blockIdx.y;
  int h = bh & (H_ - 1), b = bh >> 4;
  int q0 = qb * 64;
  int tid = threadIdx.x;
  int lane = tid & 63, wq = tid >> 6;
  int lr16 = lane & 15, kg = lane >> 4;

  // Q A-fragments: row = lr16, d-slice = half*32 + kg*8
  size_t qoff = (size_t)(b * T_ + q0 + wq * 16 + lr16) * 3 * D_ + h * HD_;
  f16x8 aq0 = *(const f16x8*)(qkv + qoff + kg * 8);
  f16x8 aq1 = *(const f16x8*)(qkv + qoff + 32 + kg * 8);

  // staging geometry: wave wq, call c: rows c*32 + wq*8 + (lane>>3), col8 = lane&7
  int sr = wq * 8 + (lane >> 3);
  int sc8 = lane & 7;

  f32x4 acc[4] = {};
  float mi[4], li[4];
  #pragma unroll
  for (int r = 0; r < 4; ++r) { mi[r] = -INFINITY; li[r] = 0.f; }

  char* Pw = PsB + wq * 2048;

  for (int k0 = 0; k0 <= q0; k0 += 64) {
    __syncthreads();   // previous chunk's LDS reads complete
    #pragma unroll
    for (int c = 0; c < 2; ++c) {
      int rw = c * 32 + sr;
      int colsw = (sc8 ^ (rw & 7)) * 8;     // pre-swizzled global column
      const f16* gk = qkv + ((size_t)(b * T_ + k0 + rw) * 3 + 1) * D_
                      + h * HD_ + colsw;
      gld16(gk, (f16*)(KsB + (size_t)(c * 32 + wq * 8) * 128));
      const f16* gv = vt + ((size_t)bh * HD_ + rw) * T_ + k0 + colsw;
      gld16(gv, (f16*)(VsB + (size_t)(c * 32 + wq * 8) * 128));
    }
    __syncthreads();   // vmcnt(0) drain + barrier: K/V chunk visible

    // S = Q K^T : 4 k-tiles x (2 MFMA over d)
    f32x4 s[4] = {};
    #pragma unroll
    for (int kt = 0; kt < 4; ++kt) {
      f16x8 kb0 = *(const f16x8*)(KsB + aswz(kt * 16 + lr16, kg * 16));
      f16x8 kb1 = *(const f16x8*)(KsB + aswz(kt * 16 + lr16, 64 + kg * 16));
      s[kt] = __builtin_amdgcn_mfma_f32_16x16x32_f16(aq0, kb0, s[kt], 0, 0, 0);
      s[kt] = __builtin_amdgcn_mfma_f32_16x16x32_f16(aq1, kb1, s[kt], 0, 0, 0);
    }

    // scale + causal mask (only diagonal chunk needs it)
    float sv[4][4];
    #pragma unroll
    for (int kt = 0; kt < 4; ++kt)
      #pragma unroll
      for (int r = 0; r < 4; ++r) sv[kt][r] = s[kt][r] * 0.125f;
    if (k0 == q0) {
      #pragma unroll
      for (int kt = 0; kt < 4; ++kt)
        #pragma unroll
        for (int r = 0; r < 4; ++r) {
          int kabs = kt * 16 + lr16;
          int qabs = wq * 16 + kg * 4 + r;
          if (kabs > qabs) sv[kt][r] = -INFINITY;
        }
    }

    // online softmax per q-row (rows live in 16-lane groups)
    #pragma unroll
    for (int r = 0; r < 4; ++r) {
      float mx = fmaxf(fmaxf(sv[0][r], sv[1][r]), fmaxf(sv[2][r], sv[3][r]));
      #pragma unroll
      for (int off = 8; off; off >>= 1) mx = fmaxf(mx, __shfl_xor(mx, off, 64));
      float nm = fmaxf(mi[r], mx);
      float alpha = __expf(mi[r] - nm);
      float rs = 0.f;
      #pragma unroll
      for (int kt = 0; kt < 4; ++kt) {
        float p = __expf(sv[kt][r] - nm);
        sv[kt][r] = p;
        rs += p;
      }
      #pragma unroll
      for (int off = 8; off; off >>= 1) rs += __shfl_xor(rs, off, 64);
      li[r] = li[r] * alpha + rs;
      mi[r] = nm;
      #pragma unroll
      for (int dt = 0; dt < 4; ++dt) acc[dt][r] *= alpha;
    }

    // P: C-layout (q=kg*4+r, k=kt*16+lr16) -> per-wave LDS (A-layout source)
    #pragma unroll
    for (int kt = 0; kt < 4; ++kt)
      #pragma unroll
      for (int r = 0; r < 4; ++r)
        *(f16*)(Pw + aswz(kg * 4 + r, (kt * 16 + lr16) * 2)) = (f16)sv[kt][r];

    // PV: O += P @ (V^T)^T  (B-frags = rows of V^T)
    #pragma unroll
    for (int ks = 0; ks < 2; ++ks) {
      f16x8 pa = *(const f16x8*)(Pw + aswz(lr16, ks * 64 + kg * 16));
      #pragma unroll
      for (int dt = 0; dt < 4; ++dt) {
        f16x8 vb = *(const f16x8*)(VsB + aswz(dt * 16 + lr16, ks * 64 + kg * 16));
        acc[dt] = __builtin_amdgcn_mfma_f32_16x16x32_f16(pa, vb, acc[dt], 0, 0, 0);
      }
    }
  }

  // epilogue: O / l -> fp16
  #pragma unroll
  for (int dt = 0; dt < 4; ++dt)
    #pragma unroll
    for (int r = 0; r < 4; ++r) {
      int q = q0 + wq * 16 + kg * 4 + r;
      yh[(size_t)(b * T_ + q) * D_ + h * HD_ + dt * 16 + lr16] =
          (f16)(acc[dt][r] / li[r]);
    }
}

// ---------------------------------------------------------------------------
// FFN elementwise: g = silu(g) * u   (fp16, 4 elems/thread)
// ---------------------------------------------------------------------------
__global__ __launch_bounds__(256) void silu_mul_kernel(
    f16* __restrict__ g, const f16* __restrict__ u, long n4) {
  long i = (long)blockIdx.x * 256 + threadIdx.x;
  if (i < n4) {
    f16x4 gv = ((const f16x4*)g)[i];
    f16x4 uv = ((const f16x4*)u)[i];
    f16x4 o;
    #pragma unroll
    for (int j = 0; j < 4; ++j) {
      float gf = (float)gv[j];
      float sf = gf / (1.f + __expf(-gf));
      o[j] = (f16)(sf * (float)uv[j]);
    }
    ((f16x4*)g)[i] = o;
  }
}

// ---------------------------------------------------------------------------
extern "C" void kernel_launch(void* const* d_in, const int* in_sizes, int n_in,
                              void* d_out, int out_size, void* d_ws,
                              size_t ws_size, hipStream_t stream) {
  const int* idx = (const int*)d_in[0];
  const float* emb = (const float*)d_in[1];
  const float* ln1 = (const float*)d_in[2];
  const float* qkvw = (const float*)d_in[3];
  const float* ow  = (const float*)d_in[4];
  const float* ln2 = (const float*)d_in[5];
  const float* gw  = (const float*)d_in[6];
  const float* uw  = (const float*)d_in[7];
  const float* dw  = (const float*)d_in[8];
  const float* lnf = (const float*)d_in[9];
  float* out = (float*)d_out;

  // workspace carve (149,422,080 B; proven available)
  char* p = (char*)d_ws;
  float* x   = (float*)p;  p += (size_t)M_ * D_ * 4;        // fp32 residual
  f16* qkvh  = (f16*)p;    p += (size_t)M_ * 3 * D_ * 2;    // fp16 qkv
  f16* hh    = (f16*)p;    p += (size_t)M_ * D_ * 2;        // fp16 h / y
  f16* gateh = (f16*)p;    p += (size_t)M_ * DI_ * 2;
  f16* uph   = (f16*)p;    p += (size_t)M_ * DI_ * 2;
  f16* wcast = (f16*)p;    // 64 MB scratch: per-layer weights / emb
  f16* vtb   = gateh;      // V^T buffer (8 MB) aliases gateh: disjoint lifetime

  embed_kernel<<<M_, 256, 0, stream>>>(idx, emb, x);

  for (int l = 0; l < L_; ++l) {
    f16* wq   = wcast;
    f16* wo_h = wq   + (size_t)3 * D_ * D_;
    f16* wg_h = wo_h + (size_t)D_ * D_;
    f16* wu_h = wg_h + (size_t)DI_ * D_;
    f16* wd_h = wu_h + (size_t)DI_ * D_;
    cast_f16_kernel<<<2048, 256, 0, stream>>>(qkvw + (size_t)l * 3 * D_ * D_, wq,   (long)(3 * D_ * D_ / 4));
    cast_f16_kernel<<<2048, 256, 0, stream>>>(ow   + (size_t)l * D_ * D_,     wo_h, (long)(D_ * D_ / 4));
    cast_f16_kernel<<<2048, 256, 0, stream>>>(gw   + (size_t)l * DI_ * D_,    wg_h, (long)(DI_ * D_ / 4));
    cast_f16_kernel<<<2048, 256, 0, stream>>>(uw   + (size_t)l * DI_ * D_,    wu_h, (long)(DI_ * D_ / 4));
    cast_f16_kernel<<<2048, 256, 0, stream>>>(dw   + (size_t)l * D_ * DI_,    wd_h, (long)(D_ * DI_ / 4));

    // h = rmsnorm(x, ln1) -> fp16
    rmsnorm_kernel<<<M_, 256, 0, stream>>>(x, ln1 + (size_t)l * D_, hh);
    // qkv = h @ qkv_w^T (fp16 out)
    gemm_f16<<<(3 * D_ / BN) * (M_ / BM), 256, 0, stream>>>(
        hh, wq, qkvh, nullptr, 3 * D_, D_, 3 * D_ / BN, 2);
    // V^T for attention (into gateh-aliased buffer)
    vtrans_kernel<<<dim3(T_ / 64, B_ * H_), 256, 0, stream>>>(qkvh, vtb);
    // attention -> hh (fp16)
    attn_mfma_kernel<<<dim3(B_ * H_, T_ / 64), 256, 0, stream>>>(qkvh, vtb, hh);
    // x = x + y @ o_w^T
    gemm_f16<<<(D_ / BN) * (M_ / BM), 256, 0, stream>>>(
        hh, wo_h, x, x, D_, D_, D_ / BN, 1);
    // h = rmsnorm(x, ln2) -> fp16
    rmsnorm_kernel<<<M_, 256, 0, stream>>>(x, ln2 + (size_t)l * D_, hh);
    // gate/up (fp16 out)
    gemm_f16<<<(DI_ / BN) * (M_ / BM), 256, 0, stream>>>(
        hh, wg_h, gateh, nullptr, DI_, D_, DI_ / BN, 2);
    gemm_f16<<<(DI_ / BN) * (M_ / BM), 256, 0, stream>>>(
        hh, wu_h, uph, nullptr, DI_, D_, DI_ / BN, 2);
    // gate = silu(gate) * up
    silu_mul_kernel<<<8192, 256, 0, stream>>>(gateh, uph, (long)((size_t)M_ * DI_ / 4));
    // x = x + gate @ down_w^T
    gemm_f16<<<(D_ / BN) * (M_ / BM), 256, 0, stream>>>(
        gateh, wd_h, x, x, D_, DI_, D_ / BN, 1);
  }

  // final norm + logits (fp32 out)
  rmsnorm_kernel<<<M_, 256, 0, stream>>>(x, lnf, hh);
  cast_f16_kernel<<<2048, 256, 0, stream>>>(emb, wcast, (long)((size_t)VOCAB_ * D_ / 4));
  gemm_f16<<<(VOCAB_ / BN) * (M_ / BM), 256, 0, stream>>>(
      hh, wcast, out, nullptr, VOCAB_, D_, VOCAB_ / BN, 0);
}